// Round 1
// baseline (535.036 us; speedup 1.0000x reference)
//
#include <hip/hip_runtime.h>
#include <hip/hip_bf16.h>

#define DIM 64

// ---------------------------------------------------------------------------
// Detect whether edge_index arrived as int64 (high dwords of first 256 values
// all zero) or int32. Result (1 = int64) written to *flag. Runs every call.
// ---------------------------------------------------------------------------
__global__ void detect_kernel(const unsigned int* __restrict__ ei, int* __restrict__ flag) {
    if (blockIdx.x == 0 && threadIdx.x == 0) {
        int is64 = 1;
        #pragma unroll 1
        for (int e = 0; e < 256; ++e) {
            if (ei[2 * e + 1] != 0u) { is64 = 0; break; }
        }
        *flag = is64;
    }
}

// ---------------------------------------------------------------------------
// Zero-init helper for deg (d_ws is poisoned with 0xAA before every call).
// ---------------------------------------------------------------------------
__global__ void zero_kernel(float* __restrict__ p, int n) {
    int i = blockIdx.x * blockDim.x + threadIdx.x;
    if (i < n) p[i] = 0.0f;
}

// ---------------------------------------------------------------------------
// Scatter: one wave per edge. lane d: agg[row*64+d] += x[col*64+d] (atomic).
// lane 0 additionally counts degree. Wave-uniform branch on index dtype.
// ---------------------------------------------------------------------------
__global__ void __launch_bounds__(256) scatter_kernel(
    const float* __restrict__ x, const void* __restrict__ eiv,
    float* __restrict__ agg, float* __restrict__ deg,
    int nE, const int* __restrict__ flag) {
    const int lane = threadIdx.x & 63;
    const int wid  = (int)((blockIdx.x * blockDim.x + threadIdx.x) >> 6);
    const int nw   = (int)((gridDim.x * blockDim.x) >> 6);
    const int is64 = *flag;

    if (is64) {
        const long long* ei = (const long long*)eiv;
        for (int e = wid; e < nE; e += nw) {
            int r = (int)ei[e];
            int c = (int)ei[nE + e];
            atomicAdd(&agg[(size_t)r * DIM + lane], x[(size_t)c * DIM + lane]);
            if (lane == 0) atomicAdd(&deg[r], 1.0f);
        }
    } else {
        const int* ei = (const int*)eiv;
        for (int e = wid; e < nE; e += nw) {
            int r = ei[e];
            int c = ei[nE + e];
            atomicAdd(&agg[(size_t)r * DIM + lane], x[(size_t)c * DIM + lane]);
            if (lane == 0) atomicAdd(&deg[r], 1.0f);
        }
    }
}

// ---------------------------------------------------------------------------
// Finalize (in place: agg aliases out): out_row = (agg_row / max(deg,1)) @ W^T + b
// Each thread holds one W column (64 VGPRs, statically indexed); the agg row
// is broadcast through a per-wave LDS buffer (no cross-wave sync needed).
// ---------------------------------------------------------------------------
__global__ void __launch_bounds__(256) finalize_kernel(
    const float* __restrict__ agg, const float* __restrict__ deg,
    const float* __restrict__ W, const float* __restrict__ b,
    float* __restrict__ out, int n) {
    __shared__ float rowbuf[4][DIM];
    const int group = threadIdx.x >> 6;
    const int lane  = threadIdx.x & 63;

    // wc[k] = W[lane][k]  (thread's output column of W^T)
    float wc[DIM];
    #pragma unroll
    for (int k4 = 0; k4 < DIM / 4; ++k4) {
        float4 w4 = *(const float4*)&W[(size_t)lane * DIM + k4 * 4];
        wc[k4 * 4 + 0] = w4.x; wc[k4 * 4 + 1] = w4.y;
        wc[k4 * 4 + 2] = w4.z; wc[k4 * 4 + 3] = w4.w;
    }
    const float bl = b[lane];

    for (int base = blockIdx.x * 4; base < n; base += gridDim.x * 4) {
        const int r = base + group;
        float a = 0.0f;
        if (r < n) {
            float dg = deg[r];
            dg = dg > 1.0f ? dg : 1.0f;
            a = agg[(size_t)r * DIM + lane] / dg;
        }
        // per-wave LDS broadcast; DS ops are in-order within a wave
        rowbuf[group][lane] = a;
        float acc = 0.0f;
        #pragma unroll
        for (int k = 0; k < DIM; ++k) acc += rowbuf[group][k] * wc[k];
        if (r < n) out[(size_t)r * DIM + lane] = acc + bl;
    }
}

extern "C" void kernel_launch(void* const* d_in, const int* in_sizes, int n_in,
                              void* d_out, int out_size, void* d_ws, size_t ws_size,
                              hipStream_t stream) {
    const float* x  = (const float*)d_in[0];
    const void*  ei = (const void*)d_in[1];
    const float* W  = (const float*)d_in[2];
    const float* b  = (const float*)d_in[3];
    float* out = (float*)d_out;

    const int n  = in_sizes[0] / DIM;   // 100000
    const int nE = in_sizes[1] / 2;     // 1600000

    float* agg  = out;                  // accumulate in place in d_out
    float* deg  = (float*)d_ws;         // n floats
    int*   flag = (int*)((char*)d_ws + (size_t)n * sizeof(float));

    // zero agg (d_out is poisoned) and deg
    hipMemsetAsync(agg, 0, (size_t)out_size * sizeof(float), stream);
    zero_kernel<<<(n + 255) / 256, 256, 0, stream>>>(deg, n);

    detect_kernel<<<1, 64, 0, stream>>>((const unsigned int*)ei, flag);

    scatter_kernel<<<2048, 256, 0, stream>>>(x, ei, agg, deg, nE, flag);

    finalize_kernel<<<2048, 256, 0, stream>>>(agg, deg, W, b, out, n);
}

// Round 2
// 395.451 us; speedup vs baseline: 1.3530x; 1.3530x over previous
//
#include <hip/hip_runtime.h>
#include <hip/hip_bf16.h>

#define DIM 64

// ---------------------------------------------------------------------------
// Detect whether edge_index arrived as int64 (high dwords of first 256 values
// all zero) or int32. Result (1 = int64) written to *flag. Runs every call.
// ---------------------------------------------------------------------------
__global__ void detect_kernel(const unsigned int* __restrict__ ei, int* __restrict__ flag) {
    if (blockIdx.x == 0 && threadIdx.x == 0) {
        int is64 = 1;
        #pragma unroll 1
        for (int e = 0; e < 256; ++e) {
            if (ei[2 * e + 1] != 0u) { is64 = 0; break; }
        }
        *flag = is64;
    }
}

// ---------------------------------------------------------------------------
// CSR path kernel 1: histogram of destination rows (int atomics).
// ---------------------------------------------------------------------------
__global__ void __launch_bounds__(256) hist_kernel(
    const void* __restrict__ eiv, int* __restrict__ cnt,
    int nE, const int* __restrict__ flag) {
    const int e = blockIdx.x * 256 + threadIdx.x;
    if (e >= nE) return;
    int r;
    if (*flag) r = (int)((const long long*)eiv)[e];
    else       r = ((const int*)eiv)[e];
    atomicAdd(&cnt[r], 1);
}

// ---------------------------------------------------------------------------
// Exclusive scan, hierarchical. scan1: 1024 elems/block (256 thr x 4),
// writes partial exclusive prefix into cursor[] and block total to blksums.
// ---------------------------------------------------------------------------
__global__ void __launch_bounds__(256) scan1_kernel(
    const int* __restrict__ cnt, int* __restrict__ cursor,
    int* __restrict__ blksums, int n) {
    __shared__ int tmp[256];
    const int t = threadIdx.x;
    const int base = blockIdx.x * 1024 + t * 4;
    int v0 = (base + 0 < n) ? cnt[base + 0] : 0;
    int v1 = (base + 1 < n) ? cnt[base + 1] : 0;
    int v2 = (base + 2 < n) ? cnt[base + 2] : 0;
    int v3 = (base + 3 < n) ? cnt[base + 3] : 0;
    const int s = v0 + v1 + v2 + v3;
    tmp[t] = s;
    __syncthreads();
    for (int off = 1; off < 256; off <<= 1) {
        int v = 0;
        if (t >= off) v = tmp[t - off];
        __syncthreads();
        tmp[t] += v;
        __syncthreads();
    }
    const int excl = tmp[t] - s;
    if (t == 255) blksums[blockIdx.x] = tmp[255];
    if (base + 0 < n) cursor[base + 0] = excl;
    if (base + 1 < n) cursor[base + 1] = excl + v0;
    if (base + 2 < n) cursor[base + 2] = excl + v0 + v1;
    if (base + 3 < n) cursor[base + 3] = excl + v0 + v1 + v2;
}

// scan2: single block exclusive-scans blksums (nblk <= 1024) in place.
__global__ void __launch_bounds__(1024) scan2_kernel(int* __restrict__ blksums, int nblk) {
    __shared__ int tmp[1024];
    const int t = threadIdx.x;
    const int v = (t < nblk) ? blksums[t] : 0;
    tmp[t] = v;
    __syncthreads();
    for (int off = 1; off < 1024; off <<= 1) {
        int u = 0;
        if (t >= off) u = tmp[t - off];
        __syncthreads();
        tmp[t] += u;
        __syncthreads();
    }
    if (t < nblk) blksums[t] = tmp[t] - v;
}

// scan3: add scanned block offsets back.
__global__ void __launch_bounds__(256) scan3_kernel(
    int* __restrict__ cursor, const int* __restrict__ blksums, int n) {
    const int add = blksums[blockIdx.x];
    const int base = blockIdx.x * 1024 + threadIdx.x * 4;
    if (base + 0 < n) cursor[base + 0] += add;
    if (base + 1 < n) cursor[base + 1] += add;
    if (base + 2 < n) cursor[base + 2] += add;
    if (base + 3 < n) cursor[base + 3] += add;
}

// ---------------------------------------------------------------------------
// CSR build: place each edge's col into its row's segment.
// After this kernel, cursor[r] == segment end for row r.
// ---------------------------------------------------------------------------
__global__ void __launch_bounds__(256) build_kernel(
    const void* __restrict__ eiv, int* __restrict__ cursor,
    int* __restrict__ scol, int nE, const int* __restrict__ flag) {
    const int e = blockIdx.x * 256 + threadIdx.x;
    if (e >= nE) return;
    int r, c;
    if (*flag) {
        r = (int)((const long long*)eiv)[e];
        c = (int)((const long long*)eiv)[nE + e];
    } else {
        r = ((const int*)eiv)[e];
        c = ((const int*)eiv)[nE + e];
    }
    const int pos = atomicAdd(&cursor[r], 1);
    scol[pos] = c;
}

// ---------------------------------------------------------------------------
// Fused gather + mean + (row @ W^T + b). One wave per node (grid-stride).
// Lane d accumulates feature d across the node's edges in a register, then
// the per-wave LDS broadcast distributes the mean row for the dot products.
// ---------------------------------------------------------------------------
__global__ void __launch_bounds__(256) gather_finalize_kernel(
    const float* __restrict__ x, const int* __restrict__ scol,
    const int* __restrict__ cursor, const int* __restrict__ cnt,
    const float* __restrict__ W, const float* __restrict__ b,
    float* __restrict__ out, int n) {
    __shared__ __align__(16) float rowbuf[4][DIM];
    const int group = threadIdx.x >> 6;
    const int lane  = threadIdx.x & 63;
    const int wid   = (int)((blockIdx.x * blockDim.x + threadIdx.x) >> 6);
    const int nw    = (int)((gridDim.x * blockDim.x) >> 6);

    // wc[k] = W[lane][k]  (thread's output column of W^T)
    float wc[DIM];
    #pragma unroll
    for (int k4 = 0; k4 < DIM / 4; ++k4) {
        float4 w4 = *(const float4*)&W[(size_t)lane * DIM + k4 * 4];
        wc[k4 * 4 + 0] = w4.x; wc[k4 * 4 + 1] = w4.y;
        wc[k4 * 4 + 2] = w4.z; wc[k4 * 4 + 3] = w4.w;
    }
    const float bl = b[lane];

    for (int r = wid; r < n; r += nw) {
        const int k   = cnt[r];
        const int end = cursor[r];
        const int s   = end - k;
        float a0 = 0.0f, a1 = 0.0f;
        int j = 0;
        for (; j + 3 < k; j += 4) {
            const int c0 = scol[s + j + 0];
            const int c1 = scol[s + j + 1];
            const int c2 = scol[s + j + 2];
            const int c3 = scol[s + j + 3];
            a0 += x[(size_t)c0 * DIM + lane];
            a1 += x[(size_t)c1 * DIM + lane];
            a0 += x[(size_t)c2 * DIM + lane];
            a1 += x[(size_t)c3 * DIM + lane];
        }
        for (; j < k; ++j) {
            const int c = scol[s + j];
            a0 += x[(size_t)c * DIM + lane];
        }
        const float dg   = (k > 0) ? (float)k : 1.0f;
        const float mean = (a0 + a1) / dg;

        rowbuf[group][lane] = mean;   // per-wave broadcast; DS ops in wave order
        float dot = bl;
        #pragma unroll
        for (int k4 = 0; k4 < DIM / 4; ++k4) {
            const float4 m4 = *(const float4*)&rowbuf[group][k4 * 4];
            dot += m4.x * wc[k4 * 4 + 0];
            dot += m4.y * wc[k4 * 4 + 1];
            dot += m4.z * wc[k4 * 4 + 2];
            dot += m4.w * wc[k4 * 4 + 3];
        }
        out[(size_t)r * DIM + lane] = dot;
    }
}

// ---------------------------------------------------------------------------
// Fallback path (round-1 kernels) in case ws_size is too small for CSR.
// ---------------------------------------------------------------------------
__global__ void zero_kernel(float* __restrict__ p, int n) {
    int i = blockIdx.x * blockDim.x + threadIdx.x;
    if (i < n) p[i] = 0.0f;
}

__global__ void __launch_bounds__(256) scatter_kernel(
    const float* __restrict__ x, const void* __restrict__ eiv,
    float* __restrict__ agg, float* __restrict__ deg,
    int nE, const int* __restrict__ flag) {
    const int lane = threadIdx.x & 63;
    const int wid  = (int)((blockIdx.x * blockDim.x + threadIdx.x) >> 6);
    const int nw   = (int)((gridDim.x * blockDim.x) >> 6);
    const int is64 = *flag;
    if (is64) {
        const long long* ei = (const long long*)eiv;
        for (int e = wid; e < nE; e += nw) {
            int r = (int)ei[e];
            int c = (int)ei[nE + e];
            atomicAdd(&agg[(size_t)r * DIM + lane], x[(size_t)c * DIM + lane]);
            if (lane == 0) atomicAdd(&deg[r], 1.0f);
        }
    } else {
        const int* ei = (const int*)eiv;
        for (int e = wid; e < nE; e += nw) {
            int r = ei[e];
            int c = ei[nE + e];
            atomicAdd(&agg[(size_t)r * DIM + lane], x[(size_t)c * DIM + lane]);
            if (lane == 0) atomicAdd(&deg[r], 1.0f);
        }
    }
}

__global__ void __launch_bounds__(256) finalize_kernel(
    const float* __restrict__ agg, const float* __restrict__ deg,
    const float* __restrict__ W, const float* __restrict__ b,
    float* __restrict__ out, int n) {
    __shared__ __align__(16) float rowbuf[4][DIM];
    const int group = threadIdx.x >> 6;
    const int lane  = threadIdx.x & 63;
    float wc[DIM];
    #pragma unroll
    for (int k4 = 0; k4 < DIM / 4; ++k4) {
        float4 w4 = *(const float4*)&W[(size_t)lane * DIM + k4 * 4];
        wc[k4 * 4 + 0] = w4.x; wc[k4 * 4 + 1] = w4.y;
        wc[k4 * 4 + 2] = w4.z; wc[k4 * 4 + 3] = w4.w;
    }
    const float bl = b[lane];
    for (int base = blockIdx.x * 4; base < n; base += gridDim.x * 4) {
        const int r = base + group;
        float a = 0.0f;
        if (r < n) {
            float dg = deg[r];
            dg = dg > 1.0f ? dg : 1.0f;
            a = agg[(size_t)r * DIM + lane] / dg;
        }
        rowbuf[group][lane] = a;
        float acc = 0.0f;
        #pragma unroll
        for (int k = 0; k < DIM; ++k) acc += rowbuf[group][k] * wc[k];
        if (r < n) out[(size_t)r * DIM + lane] = acc + bl;
    }
}

extern "C" void kernel_launch(void* const* d_in, const int* in_sizes, int n_in,
                              void* d_out, int out_size, void* d_ws, size_t ws_size,
                              hipStream_t stream) {
    const float* x  = (const float*)d_in[0];
    const void*  ei = (const void*)d_in[1];
    const float* W  = (const float*)d_in[2];
    const float* b  = (const float*)d_in[3];
    float* out = (float*)d_out;

    const int n  = in_sizes[0] / DIM;   // 100000
    const int nE = in_sizes[1] / 2;     // 1600000

    // ws layout (ints): cnt[n] | cursor[n] | blksums[1024] | flag | pad | scol[nE]
    int* wsI     = (int*)d_ws;
    int* cnt     = wsI;
    int* cursor  = wsI + n;
    int* blksums = wsI + 2 * n;
    int* flag    = wsI + 2 * n + 1024;
    int* scol    = wsI + 2 * n + 1088;
    const size_t need = ((size_t)2 * n + 1088 + (size_t)nE) * sizeof(int);

    if (ws_size >= need) {
        const int nblk = (n + 1023) / 1024;   // 98
        detect_kernel<<<1, 64, 0, stream>>>((const unsigned int*)ei, flag);
        hipMemsetAsync(cnt, 0, (size_t)n * sizeof(int), stream);
        hist_kernel <<<(nE + 255) / 256, 256, 0, stream>>>(ei, cnt, nE, flag);
        scan1_kernel<<<nblk, 256, 0, stream>>>(cnt, cursor, blksums, n);
        scan2_kernel<<<1, 1024, 0, stream>>>(blksums, nblk);
        scan3_kernel<<<nblk, 256, 0, stream>>>(cursor, blksums, n);
        build_kernel<<<(nE + 255) / 256, 256, 0, stream>>>(ei, cursor, scol, nE, flag);
        gather_finalize_kernel<<<2048, 256, 0, stream>>>(x, scol, cursor, cnt, W, b, out, n);
    } else {
        // Fallback: round-1 atomic path (needs only n floats + flag in ws)
        float* agg  = out;
        float* deg  = (float*)d_ws;
        int*   fl   = (int*)((char*)d_ws + (size_t)n * sizeof(float));
        hipMemsetAsync(agg, 0, (size_t)out_size * sizeof(float), stream);
        zero_kernel<<<(n + 255) / 256, 256, 0, stream>>>(deg, n);
        detect_kernel<<<1, 64, 0, stream>>>((const unsigned int*)ei, fl);
        scatter_kernel<<<2048, 256, 0, stream>>>(x, ei, agg, deg, nE, fl);
        finalize_kernel<<<2048, 256, 0, stream>>>(agg, deg, W, b, out, n);
    }
}